// Round 15
// baseline (264.500 us; speedup 1.0000x reference)
//
#include <hip/hip_runtime.h>
#include <cstdint>
#include <cstddef>

#define LSEQ 4096
#define DMODEL 1152
#define NH 16
#define HD 72
#define HP96 96
#define HP80 80
#define NQKV 3456

typedef unsigned short u16;
typedef unsigned int u32;
typedef __attribute__((ext_vector_type(4))) float f32x4;
typedef __attribute__((ext_vector_type(4))) u32 u32x4;
typedef _Float16 f16x8 __attribute__((ext_vector_type(8), may_alias));
typedef unsigned short us8 __attribute__((ext_vector_type(8), may_alias));
typedef unsigned short us4 __attribute__((ext_vector_type(4), may_alias));

static __device__ __forceinline__ u16 f2h(float f) {
  _Float16 h = (_Float16)f;  // RTE
  return __builtin_bit_cast(u16, h);
}
static __device__ __forceinline__ float h2f(u16 b) {
  return (float)__builtin_bit_cast(_Float16, b);
}

// Raw v_exp_f32 (libm exp2f = ocml slow path; inputs in [-60,8], no denormals).
static __device__ __forceinline__ float fast_exp2(float x) {
#if __has_builtin(__builtin_amdgcn_exp2f)
  return __builtin_amdgcn_exp2f(x);
#else
  float r;
  asm("v_exp_f32 %0, %1" : "=v"(r) : "v"(x));
  return r;
#endif
}

// ---------------- dst[n][k] = (f16) src[k][n]  (weight transpose) ----------------
__global__ void k_transp_w(const float* __restrict__ src, u16* __restrict__ dst, int K, int N) {
  __shared__ float tile[32][33];
  int tx = threadIdx.x & 31, ty = threadIdx.x >> 5;
  int n0 = blockIdx.x * 32, k0 = blockIdx.y * 32;
#pragma unroll
  for (int j = 0; j < 4; ++j)
    tile[ty + j * 8][tx] = src[(size_t)(k0 + ty + j * 8) * N + n0 + tx];
  __syncthreads();
#pragma unroll
  for (int j = 0; j < 4; ++j)
    dst[(size_t)(n0 + ty + j * 8) * K + k0 + tx] = f2h(tile[tx][ty + j * 8]);
}

// ---------------- C[M][N] = A[M][K] @ Bt[N][K]^T (+bias) ----------------
// R13 structure (double-buffered LDS + single lgkmcnt(0)-only barrier; reg prefetch stays
// in flight across the barrier) + R14 XCD swizzle + fused A-modes:
//   AMODE 0: A is f16.
//   AMODE 1: A is f32, RTE-cast during ds_write (QKV GEMM; deletes the cvt pass).
//   AMODE 2: A = combine(pbuf half0, half1, dmb) computed during staging (O-proj GEMM;
//            deletes the k_combine kernel + attb round-trip). Requires K==DMODEL,
//            M==LSEQ. head(col) via magic-div (c*233017)>>24 == c/72 for c<1152.
//            dm pairs are prefetched alongside A so their latency crosses the barrier.
template <bool OUTF32, int AMODE>
__global__ __launch_bounds__(256) void k_gemm_bt(
    const void* __restrict__ Av, const u16* __restrict__ Bt,
    const float* __restrict__ bias, const float2* __restrict__ dmv,
    void* __restrict__ Cout, int M, int N, int K, int nbx, int nwg) {
  __shared__ __align__(16) u16 sA[2][128][40];
  __shared__ __align__(16) u16 sB[2][128][40];
  int t = threadIdx.x;
  int l = t & 63, w = t >> 6, lo = l & 15, hi = l >> 4;
  int wg = blockIdx.x;
  int wgid = (wg & 7) * (nwg >> 3) + (wg >> 3);  // bijective XCD chunking
  int bx = wgid % nbx, by = wgid / nbx;
  int m0 = by * 128, n0 = bx * 128;
  int wm = (w >> 1) * 64, wn = (w & 1) * 64;
  int sr = t >> 1, sh = (t & 1) * 16;
  const u16* pb = Bt + (size_t)(n0 + sr) * K + sh;
  f32x4 acc[4][4] = {};
  const float L2E = 1.4426950408889634f;

  us8 ra0, ra1;                 // AMODE 0
  float4 fa0, fa1, fa2, fa3;    // AMODE 1
  us8 a00, a01, a10, a11;       // AMODE 2: half0/half1, two 8-col groups
  float2 dA0, dA1, dB0, dB1;    // AMODE 2: (d,m) for head-at-c0 and head-at-c0+15
  int bcol_c = 0;
  const u16* pa16 = nullptr;
  const float* pa32 = nullptr;
  const u16 *pA0 = nullptr, *pA1 = nullptr;
  const float2 *dmr0 = nullptr, *dmr1 = nullptr;

  if constexpr (AMODE == 1) {
    pa32 = (const float*)Av + (size_t)(m0 + sr) * K + sh;
    fa0 = *(const float4*)(pa32);      fa1 = *(const float4*)(pa32 + 4);
    fa2 = *(const float4*)(pa32 + 8);  fa3 = *(const float4*)(pa32 + 12);
  } else if constexpr (AMODE == 2) {
    int row = m0 + sr;
    pA0 = (const u16*)Av + (size_t)row * K + sh;
    pA1 = pA0 + (size_t)LSEQ * K;
    dmr0 = dmv + row;
    dmr1 = dmv + (size_t)NH * LSEQ + row;
    int h0 = (sh * 233017) >> 24, h15 = ((sh + 15) * 233017) >> 24;
    a00 = *(const us8*)(pA0); a01 = *(const us8*)(pA0 + 8);
    a10 = *(const us8*)(pA1); a11 = *(const us8*)(pA1 + 8);
    dA0 = dmr0[(size_t)h0 * LSEQ];  dA1 = dmr1[(size_t)h0 * LSEQ];
    dB0 = dmr0[(size_t)h15 * LSEQ]; dB1 = dmr1[(size_t)h15 * LSEQ];
    bcol_c = (h0 + 1) * HD;
  } else {
    pa16 = (const u16*)Av + (size_t)(m0 + sr) * K + sh;
    ra0 = *(const us8*)(pa16); ra1 = *(const us8*)(pa16 + 8);
  }
  us8 rb0 = *(const us8*)(pb), rb1 = *(const us8*)(pb + 8);
  int nk = K >> 5;
  for (int ks = 0; ks < nk; ++ks) {
    int buf = ks & 1;
    if constexpr (AMODE == 1) {
      us8 c0, c1;
#pragma unroll
      for (int j = 0; j < 4; ++j) {
        c0[j] = f2h(fa0[j]); c0[4 + j] = f2h(fa1[j]);
        c1[j] = f2h(fa2[j]); c1[4 + j] = f2h(fa3[j]);
      }
      *(us8*)&sA[buf][sr][sh] = c0; *(us8*)&sA[buf][sr][sh + 8] = c1;
    } else if constexpr (AMODE == 2) {
      int c0 = ks * 32 + sh;
      float Ma = fmaxf(dA0.y, dA1.y);
      float wa0 = dA0.x * fast_exp2((dA0.y - Ma) * L2E);
      float wa1 = dA1.x * fast_exp2((dA1.y - Ma) * L2E);
      float ia = 1.f / (wa0 + wa1); wa0 *= ia; wa1 *= ia;
      float Mb = fmaxf(dB0.y, dB1.y);
      float wb0 = dB0.x * fast_exp2((dB0.y - Mb) * L2E);
      float wb1 = dB1.x * fast_exp2((dB1.y - Mb) * L2E);
      float ib = 1.f / (wb0 + wb1); wb0 *= ib; wb1 *= ib;
      us8 s0, s1;
#pragma unroll
      for (int j = 0; j < 8; ++j) {
        bool b0 = (c0 + j) >= bcol_c;
        float w0 = b0 ? wb0 : wa0, w1 = b0 ? wb1 : wa1;
        s0[j] = f2h(w0 * h2f(a00[j]) + w1 * h2f(a10[j]));
        bool b1 = (c0 + 8 + j) >= bcol_c;
        float v0 = b1 ? wb0 : wa0, v1 = b1 ? wb1 : wa1;
        s1[j] = f2h(v0 * h2f(a01[j]) + v1 * h2f(a11[j]));
      }
      *(us8*)&sA[buf][sr][sh] = s0; *(us8*)&sA[buf][sr][sh + 8] = s1;
    } else {
      *(us8*)&sA[buf][sr][sh] = ra0; *(us8*)&sA[buf][sr][sh + 8] = ra1;
    }
    *(us8*)&sB[buf][sr][sh] = rb0; *(us8*)&sB[buf][sr][sh + 8] = rb1;
    if (ks + 1 < nk) {  // prefetch next tile; stays in flight across the barrier
      int off = (ks + 1) * 32;
      if constexpr (AMODE == 1) {
        fa0 = *(const float4*)(pa32 + off);      fa1 = *(const float4*)(pa32 + off + 4);
        fa2 = *(const float4*)(pa32 + off + 8);  fa3 = *(const float4*)(pa32 + off + 12);
      } else if constexpr (AMODE == 2) {
        a00 = *(const us8*)(pA0 + off); a01 = *(const us8*)(pA0 + off + 8);
        a10 = *(const us8*)(pA1 + off); a11 = *(const us8*)(pA1 + off + 8);
        int c0n = off + sh;
        int h0n = (c0n * 233017) >> 24, h15n = ((c0n + 15) * 233017) >> 24;
        dA0 = dmr0[(size_t)h0n * LSEQ];  dA1 = dmr1[(size_t)h0n * LSEQ];
        dB0 = dmr0[(size_t)h15n * LSEQ]; dB1 = dmr1[(size_t)h15n * LSEQ];
        bcol_c = (h0n + 1) * HD;
      } else {
        ra0 = *(const us8*)(pa16 + off); ra1 = *(const us8*)(pa16 + off + 8);
      }
      rb0 = *(const us8*)(pb + off); rb1 = *(const us8*)(pb + off + 8);
    }
    // single barrier: drain LDS writes only, NOT the global prefetches
    asm volatile("s_waitcnt lgkmcnt(0)" ::: "memory");
    __builtin_amdgcn_s_barrier();
    f16x8 af[4], bf[4];
#pragma unroll
    for (int mi = 0; mi < 4; ++mi) af[mi] = *(const f16x8*)&sA[buf][wm + mi * 16 + lo][hi * 8];
#pragma unroll
    for (int ni = 0; ni < 4; ++ni) bf[ni] = *(const f16x8*)&sB[buf][wn + ni * 16 + lo][hi * 8];
#pragma unroll
    for (int mi = 0; mi < 4; ++mi)
#pragma unroll
      for (int ni = 0; ni < 4; ++ni)
        acc[mi][ni] = __builtin_amdgcn_mfma_f32_16x16x32_f16(af[mi], bf[ni], acc[mi][ni], 0, 0, 0);
  }
#pragma unroll
  for (int mi = 0; mi < 4; ++mi)
#pragma unroll
    for (int ni = 0; ni < 4; ++ni) {
      int row = m0 + wm + mi * 16 + hi * 4;
      int col = n0 + wn + ni * 16 + lo;
      float bv = bias ? bias[col] : 0.0f;
#pragma unroll
      for (int rr = 0; rr < 4; ++rr) {
        float v = acc[mi][ni][rr] + bv;
        if (OUTF32) ((float*)Cout)[(size_t)(row + rr) * N + col] = v;
        else        ((u16*)Cout)[(size_t)(row + rr) * N + col] = f2h(v);
      }
    }
}

// ---------------- per-token: +bias, per-head RMSNorm, 2D RoPE, scatter to head-major ----------------
__global__ __launch_bounds__(256) void k_norm_rope(
    const u16* __restrict__ qkv,
    const float* __restrict__ q_b, const float* __restrict__ kv_b,
    const float* __restrict__ q_s, const float* __restrict__ k_s,
    u16* __restrict__ qp, u16* __restrict__ kp, u16* __restrict__ vn) {
  __shared__ float s_q[DMODEL], s_k[DMODEL], s_v[DMODEL];
  __shared__ float cs[4][18];
  int t = threadIdx.x;
  int tok = blockIdx.x;
  if (t < 36) {
    int i = t < 18 ? t : t - 18;
    float f = exp2f(-(float)i * (6.6438561897747247f / 9.0f));  // 100^(-i/9)
    float pos = (t < 18) ? (float)(tok >> 6) : (float)(tok & 63);
    float s, c;
    sincosf(pos * f, &s, &c);
    if (t < 18) { cs[0][i] = c; cs[1][i] = s; }
    else        { cs[2][i] = c; cs[3][i] = s; }
  }
  const u16* rowp = qkv + (size_t)tok * NQKV;
  for (int c = t; c < NQKV / 8; c += 256) {  // 432 us8 chunks
    int base8 = c * 8;
    us8 v = *(const us8*)(rowp + base8);
    float* dst; const float* bias; int off;
    if (c < 144)      { dst = s_q; bias = q_b;           off = base8; }
    else if (c < 288) { dst = s_k; bias = kv_b;          off = base8 - DMODEL; }
    else              { dst = s_v; bias = kv_b + DMODEL; off = base8 - 2 * DMODEL; }
#pragma unroll
    for (int j = 0; j < 8; ++j) dst[off + j] = h2f(v[j]) + bias[off + j];
  }
  __syncthreads();
  int h = t >> 4, sub = t & 15;
  int base = h * HD;
  float aq = 0, ak = 0, av = 0;
#pragma unroll
  for (int j = 0; j < 5; ++j) {
    int idx = sub + 16 * j;
    if (idx < HD) {
      float a = s_q[base + idx], b = s_k[base + idx], c = s_v[base + idx];
      aq += a * a; ak += b * b; av += c * c;
    }
  }
#pragma unroll
  for (int m = 1; m <= 8; m <<= 1) {
    aq += __shfl_xor(aq, m, 64);
    ak += __shfl_xor(ak, m, 64);
    av += __shfl_xor(av, m, 64);
  }
  float rq = rsqrtf(aq / 72.f + 1e-6f);
  float rk = rsqrtf(ak / 72.f + 1e-6f);
  float rv = rsqrtf(av / 72.f + 1e-6f);
  size_t ob96 = ((size_t)h * LSEQ + tok) * HP96;
  size_t ob80 = ((size_t)h * LSEQ + tok) * HP80;
#pragma unroll
  for (int j = 0; j < 6; ++j) {
    int idx = sub + 16 * j;
    float oq = 0.f, ok = 0.f;
    if (idx < HD) {
      int sec = idx >= 36;
      int loc = idx - sec * 36;
      int i = loc >= 18 ? loc - 18 : loc;
      float c = cs[sec * 2 + 0][i], s = cs[sec * 2 + 1][i];
      int p1 = sec * 36 + i, p2 = p1 + 18;
      float q1 = s_q[base + p1] * rq * (1.f + q_s[p1]);
      float q2 = s_q[base + p2] * rq * (1.f + q_s[p2]);
      float k1 = s_k[base + p1] * rk * (1.f + k_s[p1]);
      float k2 = s_k[base + p2] * rk * (1.f + k_s[p2]);
      if (loc < 18) { oq = q1 * c - q2 * s; ok = k1 * c - k2 * s; }
      else          { oq = q1 * s + q2 * c; ok = k1 * s + k2 * c; }
    }
    qp[ob96 + idx] = f2h(oq);
    kp[ob96 + idx] = f2h(ok);
  }
#pragma unroll
  for (int j = 0; j < 5; ++j) {
    int idx = sub + 16 * j;
    // h-slot 72 carries 1.0 so PV's MFMA accumulates the softmax denominator for free
    float ov = (idx < HD) ? s_v[base + idx] * rv : (idx == 72 ? 1.0f : 0.f);
    vn[ob80 + idx] = f2h(ov);
  }
}

// ---------------- V -> fragment-major global layout ----------------
__global__ __launch_bounds__(256) void k_vfrag(const u16* __restrict__ vn, u16* __restrict__ vf) {
  __shared__ u16 tl[32][84];  // [key_local][h] pad 80->84
  int head = blockIdx.y, kb = blockIdx.x;
  int t = threadIdx.x;
  const u16* src = vn + ((size_t)head * LSEQ + kb * 32) * HP80;
  for (int p = t; p < 32 * 20; p += 256) {
    int rr = p / 20, c4 = p % 20;
    *(us4*)&tl[rr][c4 * 4] = *(const us4*)(src + rr * HP80 + c4 * 4);
  }
  __syncthreads();
  u16* dst = vf + ((size_t)head * 128 + kb) * 2560;
  for (int u = t; u < 320; u += 256) {
    int ht = u >> 6, ll = u & 63, lo2 = ll & 15, hi2 = ll >> 4;
    us8 o;
#pragma unroll
    for (int j = 0; j < 8; ++j)
      o[j] = tl[(j >> 2) * 16 + hi2 * 4 + (j & 3)][ht * 16 + lo2];
    *(us8*)&dst[(size_t)u * 8] = o;
  }
}

// ---------------- flash attention, key-split 2: 4 waves x 32 q-rows x 2048 keys ----------------
// Frozen (R11 structure): double-buffered sK, single raw barrier with lgkmcnt(0)-only
// drain; K/V global prefetches stay in flight across the barrier. Occupancy hard-capped
// at 4 waves/SIMD by the 88-VGPR bucket — grid already delivers it.
__global__ __launch_bounds__(256, 2) void k_flash(
    const u16* __restrict__ qp, const u16* __restrict__ kp,
    const u16* __restrict__ vf, u16* __restrict__ pbuf, float2* __restrict__ dmb) {
  __shared__ __align__(16) u16 sK[2][64][104];  // double-buffered [key][hdim] pad 96->104
  int t = threadIdx.x;
  int l = t & 63, w = t >> 6, lo = l & 15, hi = l >> 4;
  int id = blockIdx.x, r = id >> 3;
  int half = r & 1, qb = (r >> 1) & 31, head = ((r >> 6) << 3) + (id & 7);
  const float L2E = 1.4426950408889634f;

  const u16* qbase = qp + ((size_t)head * LSEQ + qb * 128 + w * 32 + lo) * HP96 + hi * 8;
  f16x8 qf[2][3];
#pragma unroll
  for (int g = 0; g < 2; ++g)
#pragma unroll
    for (int c = 0; c < 3; ++c)
      qf[g][c] = *(const f16x8*)(qbase + g * 16 * HP96 + c * 32);

  f32x4 oacc[2][5] = {};
  float mrun[2];
#pragma unroll
  for (int g = 0; g < 2; ++g) mrun[g] = -__builtin_inff();

  int sr_ = t >> 2, sq4 = (t & 3) * 24;
  const u16* kptr = kp + ((size_t)head * LSEQ + half * 2048 + sr_) * HP96 + sq4;
  us8 kx0 = *(const us8*)(kptr), kx1 = *(const us8*)(kptr + 8), kx2 = *(const us8*)(kptr + 16);

  const u16* vptr = vf + ((size_t)head * 128 + half * 64) * 2560 + (size_t)l * 8;
  us8 vA[5], vB[5];
#pragma unroll
  for (int ht = 0; ht < 5; ++ht) vA[ht] = *(const us8*)(vptr + ht * 512);
  vptr += 2560;

  for (int kt = 0; kt < 32; ++kt) {
    u16* skb = &sK[kt & 1][0][0];
    *(us8*)(skb + sr_ * 104 + sq4) = kx0;
    *(us8*)(skb + sr_ * 104 + sq4 + 8) = kx1;
    *(us8*)(skb + sr_ * 104 + sq4 + 16) = kx2;
    if (kt < 31) {  // prefetch next K tile; stays in flight across the barrier
      kx0 = *(const us8*)(kptr + 6144);
      kx1 = *(const us8*)(kptr + 6144 + 8);
      kx2 = *(const us8*)(kptr + 6144 + 16);
      kptr += 6144;
    }
    asm volatile("s_waitcnt lgkmcnt(0)" ::: "memory");
    __builtin_amdgcn_s_barrier();
    const u16(*sKb)[104] = (const u16(*)[104])skb;
    f32x4 sacc[2][4] = {};
#pragma unroll
    for (int c = 0; c < 3; ++c)
#pragma unroll
      for (int nt = 0; nt < 4; ++nt) {
        f16x8 bk = *(const f16x8*)&sKb[lo + 16 * nt][c * 32 + hi * 8];
#pragma unroll
        for (int g = 0; g < 2; ++g)
          sacc[g][nt] = __builtin_amdgcn_mfma_f32_16x16x32_f16(bk, qf[g][c], sacc[g][nt], 0, 0, 0);
      }
    float mt[2];
#pragma unroll
    for (int g = 0; g < 2; ++g) {
      float m = fmaxf(fmaxf(fmaxf(sacc[g][0][0], sacc[g][0][1]), sacc[g][0][2]), sacc[g][0][3]);
#pragma unroll
      for (int nt = 1; nt < 4; ++nt)
        m = fmaxf(m, fmaxf(fmaxf(fmaxf(sacc[g][nt][0], sacc[g][nt][1]), sacc[g][nt][2]), sacc[g][nt][3]));
      m = fmaxf(m, __shfl_xor(m, 16, 64));
      m = fmaxf(m, __shfl_xor(m, 32, 64));
      mt[g] = m;
    }
    bool need = (mt[0] > mrun[0] + 8.f) | (mt[1] > mrun[1] + 8.f);
    if (__any(need)) {
#pragma unroll
      for (int g = 0; g < 2; ++g) {
        float mn = fmaxf(mrun[g], mt[g]);
        float al = fast_exp2((mrun[g] - mn) * L2E);
        mrun[g] = mn;
#pragma unroll
        for (int ht = 0; ht < 5; ++ht)
#pragma unroll
          for (int rr = 0; rr < 4; ++rr) oacc[g][ht][rr] *= al;
      }
    }
#pragma unroll
    for (int kc = 0; kc < 2; ++kc) {
#pragma unroll
      for (int ht = 0; ht < 5; ++ht) vB[ht] = *(const us8*)(vptr + ht * 512);
      vptr += 2560;  // final iteration's overrun frame lands in the (allocated) dm region
#pragma unroll
      for (int g = 0; g < 2; ++g) {
        float nm = -mrun[g] * L2E;
        float p0[4], p1[4];
#pragma unroll
        for (int rr = 0; rr < 4; ++rr) {
          p0[rr] = fast_exp2(__builtin_fmaf(sacc[g][2 * kc][rr], L2E, nm));
          p1[rr] = fast_exp2(__builtin_fmaf(sacc[g][2 * kc + 1][rr], L2E, nm));
        }
        u32x4 pw = {__builtin_bit_cast(u32, __builtin_amdgcn_cvt_pkrtz(p0[0], p0[1])),
                    __builtin_bit_cast(u32, __builtin_amdgcn_cvt_pkrtz(p0[2], p0[3])),
                    __builtin_bit_cast(u32, __builtin_amdgcn_cvt_pkrtz(p1[0], p1[1])),
                    __builtin_bit_cast(u32, __builtin_amdgcn_cvt_pkrtz(p1[2], p1[3]))};
        f16x8 pb = __builtin_bit_cast(f16x8, pw);
#pragma unroll
        for (int ht = 0; ht < 5; ++ht)
          oacc[g][ht] = __builtin_amdgcn_mfma_f32_16x16x32_f16(
              __builtin_bit_cast(f16x8, vA[ht]), pb, oacc[g][ht], 0, 0, 0);
      }
#pragma unroll
      for (int ht = 0; ht < 5; ++ht) vA[ht] = vB[ht];
    }
  }
#pragma unroll
  for (int g = 0; g < 2; ++g) {
    float den = __shfl(oacc[g][4][0], lo + 32, 64);  // h=72 ones-row -> denominator
    float inv = 1.f / den;
    int row = qb * 128 + w * 32 + g * 16 + lo;
    u16* orow = pbuf + ((size_t)half * LSEQ + row) * DMODEL + head * HD;
#pragma unroll
    for (int ht = 0; ht < 5; ++ht)
#pragma unroll
      for (int rr = 0; rr < 4; ++rr) {
        int h = 16 * ht + 4 * hi + rr;
        if (h < HD) orow[h] = f2h(oacc[g][ht][rr] * inv);
      }
    if (hi == 0) {
      float2 dm; dm.x = den; dm.y = mrun[g];
      dmb[((size_t)half * NH + head) * LSEQ + row] = dm;
    }
  }
}

extern "C" void kernel_launch(void* const* d_in, const int* in_sizes, int n_in,
                              void* d_out, int out_size, void* d_ws, size_t ws_size,
                              hipStream_t stream) {
  const float* x    = (const float*)d_in[0];
  const float* q_w  = (const float*)d_in[1];
  const float* q_b  = (const float*)d_in[2];
  const float* kv_w = (const float*)d_in[3];
  const float* kv_b = (const float*)d_in[4];
  const float* o_w  = (const float*)d_in[5];
  const float* o_b  = (const float*)d_in[6];
  const float* q_s  = (const float*)d_in[7];
  const float* k_s  = (const float*)d_in[8];
  char* ws = (char*)d_ws;
  // layout (bytes), high-water 84,017,152:
  u16* wT   = (u16*)(ws + 9437184);    // 7,962,624    [q_w^T; kv_w^T] f16 [3456][1152]
  u16* oT   = (u16*)(ws + 17399808);   // 2,654,208    o_w^T (live until GEMM2)
  u16* qkvb = (u16*)(ws + 20054016);   // 28,311,552   qkv pre-norm [4096][3456]
  u16* qp   = (u16*)(ws + 48365568);   // 12,582,912   q head-major [16][4096][96]
  u16* kp   = (u16*)(ws + 60948480);   // 12,582,912   k head-major
  u16* vn   = (u16*)(ws + 73531392);   // 10,485,760   v head-major [16][4096][80]
  u16* vfb  = (u16*)(ws + 0);          // 10,485,760   V fragment-major
  float2* dmb = (float2*)(ws + 10485760); // 1,048,576 (d,m) partials [2][16][4096]
  u16* pbuf = (u16*)(ws + 29491200);   // 18,874,368   o-hat partials [2][4096][1152]

  k_transp_w<<<dim3(36, 36), 256, 0, stream>>>(q_w, wT, DMODEL, DMODEL);
  k_transp_w<<<dim3(72, 36), 256, 0, stream>>>(kv_w, wT + (size_t)DMODEL * DMODEL, DMODEL, 2 * DMODEL);
  k_transp_w<<<dim3(36, 36), 256, 0, stream>>>(o_w, oT, DMODEL, DMODEL);
  // QKV GEMM: A = x (f32, cast fused into staging); grid 864 = 27x32, XCD-swizzled.
  k_gemm_bt<false, 1><<<864, 256, 0, stream>>>(x, wT, nullptr, nullptr, qkvb,
                                               LSEQ, NQKV, DMODEL, 27, 864);
  k_norm_rope<<<LSEQ, 256, 0, stream>>>(qkvb, q_b, kv_b, q_s, k_s, qp, kp, vn);
  k_vfrag<<<dim3(128, 16), 256, 0, stream>>>(vn, vfb);
  k_flash<<<1024, 256, 0, stream>>>(qp, kp, vfb, pbuf, dmb);
  // O-proj GEMM with the key-half combine fused into A-staging (k_combine deleted).
  k_gemm_bt<true, 2><<<288, 256, 0, stream>>>(pbuf, oT, o_b, dmb, (float*)d_out,
                                              LSEQ, DMODEL, DMODEL, 9, 288);
}

// Round 16
// 248.914 us; speedup vs baseline: 1.0626x; 1.0626x over previous
//
#include <hip/hip_runtime.h>
#include <cstdint>
#include <cstddef>

#define LSEQ 4096
#define DMODEL 1152
#define NH 16
#define HD 72
#define HP96 96
#define HP80 80
#define NQKV 3456

typedef unsigned short u16;
typedef unsigned int u32;
typedef __attribute__((ext_vector_type(4))) float f32x4;
typedef __attribute__((ext_vector_type(4))) u32 u32x4;
typedef _Float16 f16x8 __attribute__((ext_vector_type(8), may_alias));
typedef unsigned short us8 __attribute__((ext_vector_type(8), may_alias));
typedef unsigned short us4 __attribute__((ext_vector_type(4), may_alias));

static __device__ __forceinline__ u16 f2h(float f) {
  _Float16 h = (_Float16)f;  // RTE
  return __builtin_bit_cast(u16, h);
}
static __device__ __forceinline__ float h2f(u16 b) {
  return (float)__builtin_bit_cast(_Float16, b);
}

// Raw v_exp_f32 (libm exp2f = ocml slow path; inputs in [-60,8], no denormals).
static __device__ __forceinline__ float fast_exp2(float x) {
#if __has_builtin(__builtin_amdgcn_exp2f)
  return __builtin_amdgcn_exp2f(x);
#else
  float r;
  asm("v_exp_f32 %0, %1" : "=v"(r) : "v"(x));
  return r;
#endif
}

// ---------------- dst[n][k] = (f16) src[k][n]  (weight transpose) ----------------
__global__ void k_transp_w(const float* __restrict__ src, u16* __restrict__ dst, int K, int N) {
  __shared__ float tile[32][33];
  int tx = threadIdx.x & 31, ty = threadIdx.x >> 5;
  int n0 = blockIdx.x * 32, k0 = blockIdx.y * 32;
#pragma unroll
  for (int j = 0; j < 4; ++j)
    tile[ty + j * 8][tx] = src[(size_t)(k0 + ty + j * 8) * N + n0 + tx];
  __syncthreads();
#pragma unroll
  for (int j = 0; j < 4; ++j)
    dst[(size_t)(n0 + ty + j * 8) * K + k0 + tx] = f2h(tile[tx][ty + j * 8]);
}

// ---------------- C[M][N] = A[M][K] @ Bt[N][K]^T (+bias); A f16 or f32 (cast fused) ----------------
// R13 structure (double-buffered LDS + single lgkmcnt(0)-only barrier; reg prefetch stays
// in flight across the barrier) + R14 additions (best measured config, 249.1 us):
//  - AF32: A read as f32, RTE-cast during ds_write (QKV GEMM; deletes the cvt pass).
//  - 1D grid + bijective XCD swizzle (nwg%8==0): wgid=(wg&7)*(nwg/8)+(wg>>3).
// R15's combine-fusion (AMODE 2) REVERTED: at 288 blocks (~1.1/CU) the O-proj GEMM has
// no TLP to hide the fused combine's VALU+uncoalesced-dm latency; -15 us measured.
template <bool OUTF32, bool AF32>
__global__ __launch_bounds__(256) void k_gemm_bt(
    const void* __restrict__ Av, const u16* __restrict__ Bt,
    const float* __restrict__ bias, void* __restrict__ Cout,
    int M, int N, int K, int nbx, int nwg) {
  __shared__ __align__(16) u16 sA[2][128][40];
  __shared__ __align__(16) u16 sB[2][128][40];
  int t = threadIdx.x;
  int l = t & 63, w = t >> 6, lo = l & 15, hi = l >> 4;
  int wg = blockIdx.x;
  int wgid = (wg & 7) * (nwg >> 3) + (wg >> 3);  // bijective XCD chunking
  int bx = wgid % nbx, by = wgid / nbx;
  int m0 = by * 128, n0 = bx * 128;
  int wm = (w >> 1) * 64, wn = (w & 1) * 64;
  int sr = t >> 1, sh = (t & 1) * 16;
  const u16* pb = Bt + (size_t)(n0 + sr) * K + sh;
  f32x4 acc[4][4] = {};
  us8 ra0, ra1;
  float4 fa0, fa1, fa2, fa3;
  const u16* pa16 = nullptr;
  const float* pa32 = nullptr;
  if (AF32) {
    pa32 = (const float*)Av + (size_t)(m0 + sr) * K + sh;
    fa0 = *(const float4*)(pa32);      fa1 = *(const float4*)(pa32 + 4);
    fa2 = *(const float4*)(pa32 + 8);  fa3 = *(const float4*)(pa32 + 12);
  } else {
    pa16 = (const u16*)Av + (size_t)(m0 + sr) * K + sh;
    ra0 = *(const us8*)(pa16); ra1 = *(const us8*)(pa16 + 8);
  }
  us8 rb0 = *(const us8*)(pb), rb1 = *(const us8*)(pb + 8);
  int nk = K >> 5;
  for (int ks = 0; ks < nk; ++ks) {
    int buf = ks & 1;
    if (AF32) {
      us8 c0, c1;
#pragma unroll
      for (int j = 0; j < 4; ++j) {
        c0[j] = f2h(fa0[j]); c0[4 + j] = f2h(fa1[j]);
        c1[j] = f2h(fa2[j]); c1[4 + j] = f2h(fa3[j]);
      }
      *(us8*)&sA[buf][sr][sh] = c0; *(us8*)&sA[buf][sr][sh + 8] = c1;
    } else {
      *(us8*)&sA[buf][sr][sh] = ra0; *(us8*)&sA[buf][sr][sh + 8] = ra1;
    }
    *(us8*)&sB[buf][sr][sh] = rb0; *(us8*)&sB[buf][sr][sh + 8] = rb1;
    if (ks + 1 < nk) {  // prefetch next tile; stays in flight across the barrier
      int off = (ks + 1) * 32;
      if (AF32) {
        fa0 = *(const float4*)(pa32 + off);      fa1 = *(const float4*)(pa32 + off + 4);
        fa2 = *(const float4*)(pa32 + off + 8);  fa3 = *(const float4*)(pa32 + off + 12);
      } else {
        ra0 = *(const us8*)(pa16 + off); ra1 = *(const us8*)(pa16 + off + 8);
      }
      rb0 = *(const us8*)(pb + off); rb1 = *(const us8*)(pb + off + 8);
    }
    // single barrier: drain LDS writes only, NOT the global prefetches
    asm volatile("s_waitcnt lgkmcnt(0)" ::: "memory");
    __builtin_amdgcn_s_barrier();
    f16x8 af[4], bf[4];
#pragma unroll
    for (int mi = 0; mi < 4; ++mi) af[mi] = *(const f16x8*)&sA[buf][wm + mi * 16 + lo][hi * 8];
#pragma unroll
    for (int ni = 0; ni < 4; ++ni) bf[ni] = *(const f16x8*)&sB[buf][wn + ni * 16 + lo][hi * 8];
#pragma unroll
    for (int mi = 0; mi < 4; ++mi)
#pragma unroll
      for (int ni = 0; ni < 4; ++ni)
        acc[mi][ni] = __builtin_amdgcn_mfma_f32_16x16x32_f16(af[mi], bf[ni], acc[mi][ni], 0, 0, 0);
  }
#pragma unroll
  for (int mi = 0; mi < 4; ++mi)
#pragma unroll
    for (int ni = 0; ni < 4; ++ni) {
      int row = m0 + wm + mi * 16 + hi * 4;
      int col = n0 + wn + ni * 16 + lo;
      float bv = bias ? bias[col] : 0.0f;
#pragma unroll
      for (int rr = 0; rr < 4; ++rr) {
        float v = acc[mi][ni][rr] + bv;
        if (OUTF32) ((float*)Cout)[(size_t)(row + rr) * N + col] = v;
        else        ((u16*)Cout)[(size_t)(row + rr) * N + col] = f2h(v);
      }
    }
}

// ---------------- per-token: +bias, per-head RMSNorm, 2D RoPE, scatter to head-major ----------------
__global__ __launch_bounds__(256) void k_norm_rope(
    const u16* __restrict__ qkv,
    const float* __restrict__ q_b, const float* __restrict__ kv_b,
    const float* __restrict__ q_s, const float* __restrict__ k_s,
    u16* __restrict__ qp, u16* __restrict__ kp, u16* __restrict__ vn) {
  __shared__ float s_q[DMODEL], s_k[DMODEL], s_v[DMODEL];
  __shared__ float cs[4][18];
  int t = threadIdx.x;
  int tok = blockIdx.x;
  if (t < 36) {
    int i = t < 18 ? t : t - 18;
    float f = exp2f(-(float)i * (6.6438561897747247f / 9.0f));  // 100^(-i/9)
    float pos = (t < 18) ? (float)(tok >> 6) : (float)(tok & 63);
    float s, c;
    sincosf(pos * f, &s, &c);
    if (t < 18) { cs[0][i] = c; cs[1][i] = s; }
    else        { cs[2][i] = c; cs[3][i] = s; }
  }
  const u16* rowp = qkv + (size_t)tok * NQKV;
  for (int c = t; c < NQKV / 8; c += 256) {  // 432 us8 chunks
    int base8 = c * 8;
    us8 v = *(const us8*)(rowp + base8);
    float* dst; const float* bias; int off;
    if (c < 144)      { dst = s_q; bias = q_b;           off = base8; }
    else if (c < 288) { dst = s_k; bias = kv_b;          off = base8 - DMODEL; }
    else              { dst = s_v; bias = kv_b + DMODEL; off = base8 - 2 * DMODEL; }
#pragma unroll
    for (int j = 0; j < 8; ++j) dst[off + j] = h2f(v[j]) + bias[off + j];
  }
  __syncthreads();
  int h = t >> 4, sub = t & 15;
  int base = h * HD;
  float aq = 0, ak = 0, av = 0;
#pragma unroll
  for (int j = 0; j < 5; ++j) {
    int idx = sub + 16 * j;
    if (idx < HD) {
      float a = s_q[base + idx], b = s_k[base + idx], c = s_v[base + idx];
      aq += a * a; ak += b * b; av += c * c;
    }
  }
#pragma unroll
  for (int m = 1; m <= 8; m <<= 1) {
    aq += __shfl_xor(aq, m, 64);
    ak += __shfl_xor(ak, m, 64);
    av += __shfl_xor(av, m, 64);
  }
  float rq = rsqrtf(aq / 72.f + 1e-6f);
  float rk = rsqrtf(ak / 72.f + 1e-6f);
  float rv = rsqrtf(av / 72.f + 1e-6f);
  size_t ob96 = ((size_t)h * LSEQ + tok) * HP96;
  size_t ob80 = ((size_t)h * LSEQ + tok) * HP80;
#pragma unroll
  for (int j = 0; j < 6; ++j) {
    int idx = sub + 16 * j;
    float oq = 0.f, ok = 0.f;
    if (idx < HD) {
      int sec = idx >= 36;
      int loc = idx - sec * 36;
      int i = loc >= 18 ? loc - 18 : loc;
      float c = cs[sec * 2 + 0][i], s = cs[sec * 2 + 1][i];
      int p1 = sec * 36 + i, p2 = p1 + 18;
      float q1 = s_q[base + p1] * rq * (1.f + q_s[p1]);
      float q2 = s_q[base + p2] * rq * (1.f + q_s[p2]);
      float k1 = s_k[base + p1] * rk * (1.f + k_s[p1]);
      float k2 = s_k[base + p2] * rk * (1.f + k_s[p2]);
      if (loc < 18) { oq = q1 * c - q2 * s; ok = k1 * c - k2 * s; }
      else          { oq = q1 * s + q2 * c; ok = k1 * s + k2 * c; }
    }
    qp[ob96 + idx] = f2h(oq);
    kp[ob96 + idx] = f2h(ok);
  }
#pragma unroll
  for (int j = 0; j < 5; ++j) {
    int idx = sub + 16 * j;
    // h-slot 72 carries 1.0 so PV's MFMA accumulates the softmax denominator for free
    float ov = (idx < HD) ? s_v[base + idx] * rv : (idx == 72 ? 1.0f : 0.f);
    vn[ob80 + idx] = f2h(ov);
  }
}

// ---------------- V -> fragment-major global layout ----------------
// vf[head][kb32][ht][lane][8]: lane (lo=l&15, hi=l>>4), elem j holds
// V[h = 16*ht + lo][key = kb*32 + (j>>2)*16 + hi*4 + (j&3)].
__global__ __launch_bounds__(256) void k_vfrag(const u16* __restrict__ vn, u16* __restrict__ vf) {
  __shared__ u16 tl[32][84];  // [key_local][h] pad 80->84
  int head = blockIdx.y, kb = blockIdx.x;
  int t = threadIdx.x;
  const u16* src = vn + ((size_t)head * LSEQ + kb * 32) * HP80;
  for (int p = t; p < 32 * 20; p += 256) {
    int rr = p / 20, c4 = p % 20;
    *(us4*)&tl[rr][c4 * 4] = *(const us4*)(src + rr * HP80 + c4 * 4);
  }
  __syncthreads();
  u16* dst = vf + ((size_t)head * 128 + kb) * 2560;
  for (int u = t; u < 320; u += 256) {
    int ht = u >> 6, ll = u & 63, lo2 = ll & 15, hi2 = ll >> 4;
    us8 o;
#pragma unroll
    for (int j = 0; j < 8; ++j)
      o[j] = tl[(j >> 2) * 16 + hi2 * 4 + (j & 3)][ht * 16 + lo2];
    *(us8*)&dst[(size_t)u * 8] = o;
  }
}

// ---------------- flash attention, key-split 2: 4 waves x 32 q-rows x 2048 keys ----------------
// Frozen (R11 structure): double-buffered sK, single raw barrier with lgkmcnt(0)-only
// drain; K/V global prefetches stay in flight across the barrier. Occupancy hard-capped
// at 4 waves/SIMD by the 88-VGPR bucket — grid already delivers it.
__global__ __launch_bounds__(256, 2) void k_flash(
    const u16* __restrict__ qp, const u16* __restrict__ kp,
    const u16* __restrict__ vf, u16* __restrict__ pbuf, float2* __restrict__ dmb) {
  __shared__ __align__(16) u16 sK[2][64][104];  // double-buffered [key][hdim] pad 96->104
  int t = threadIdx.x;
  int l = t & 63, w = t >> 6, lo = l & 15, hi = l >> 4;
  int id = blockIdx.x, r = id >> 3;
  int half = r & 1, qb = (r >> 1) & 31, head = ((r >> 6) << 3) + (id & 7);
  const float L2E = 1.4426950408889634f;

  const u16* qbase = qp + ((size_t)head * LSEQ + qb * 128 + w * 32 + lo) * HP96 + hi * 8;
  f16x8 qf[2][3];
#pragma unroll
  for (int g = 0; g < 2; ++g)
#pragma unroll
    for (int c = 0; c < 3; ++c)
      qf[g][c] = *(const f16x8*)(qbase + g * 16 * HP96 + c * 32);

  f32x4 oacc[2][5] = {};
  float mrun[2];
#pragma unroll
  for (int g = 0; g < 2; ++g) mrun[g] = -__builtin_inff();

  int sr_ = t >> 2, sq4 = (t & 3) * 24;
  const u16* kptr = kp + ((size_t)head * LSEQ + half * 2048 + sr_) * HP96 + sq4;
  us8 kx0 = *(const us8*)(kptr), kx1 = *(const us8*)(kptr + 8), kx2 = *(const us8*)(kptr + 16);

  const u16* vptr = vf + ((size_t)head * 128 + half * 64) * 2560 + (size_t)l * 8;
  us8 vA[5], vB[5];
#pragma unroll
  for (int ht = 0; ht < 5; ++ht) vA[ht] = *(const us8*)(vptr + ht * 512);
  vptr += 2560;

  for (int kt = 0; kt < 32; ++kt) {
    u16* skb = &sK[kt & 1][0][0];
    *(us8*)(skb + sr_ * 104 + sq4) = kx0;
    *(us8*)(skb + sr_ * 104 + sq4 + 8) = kx1;
    *(us8*)(skb + sr_ * 104 + sq4 + 16) = kx2;
    if (kt < 31) {  // prefetch next K tile; stays in flight across the barrier
      kx0 = *(const us8*)(kptr + 6144);
      kx1 = *(const us8*)(kptr + 6144 + 8);
      kx2 = *(const us8*)(kptr + 6144 + 16);
      kptr += 6144;
    }
    asm volatile("s_waitcnt lgkmcnt(0)" ::: "memory");
    __builtin_amdgcn_s_barrier();
    const u16(*sKb)[104] = (const u16(*)[104])skb;
    f32x4 sacc[2][4] = {};
#pragma unroll
    for (int c = 0; c < 3; ++c)
#pragma unroll
      for (int nt = 0; nt < 4; ++nt) {
        f16x8 bk = *(const f16x8*)&sKb[lo + 16 * nt][c * 32 + hi * 8];
#pragma unroll
        for (int g = 0; g < 2; ++g)
          sacc[g][nt] = __builtin_amdgcn_mfma_f32_16x16x32_f16(bk, qf[g][c], sacc[g][nt], 0, 0, 0);
      }
    float mt[2];
#pragma unroll
    for (int g = 0; g < 2; ++g) {
      float m = fmaxf(fmaxf(fmaxf(sacc[g][0][0], sacc[g][0][1]), sacc[g][0][2]), sacc[g][0][3]);
#pragma unroll
      for (int nt = 1; nt < 4; ++nt)
        m = fmaxf(m, fmaxf(fmaxf(fmaxf(sacc[g][nt][0], sacc[g][nt][1]), sacc[g][nt][2]), sacc[g][nt][3]));
      m = fmaxf(m, __shfl_xor(m, 16, 64));
      m = fmaxf(m, __shfl_xor(m, 32, 64));
      mt[g] = m;
    }
    bool need = (mt[0] > mrun[0] + 8.f) | (mt[1] > mrun[1] + 8.f);
    if (__any(need)) {
#pragma unroll
      for (int g = 0; g < 2; ++g) {
        float mn = fmaxf(mrun[g], mt[g]);
        float al = fast_exp2((mrun[g] - mn) * L2E);
        mrun[g] = mn;
#pragma unroll
        for (int ht = 0; ht < 5; ++ht)
#pragma unroll
          for (int rr = 0; rr < 4; ++rr) oacc[g][ht][rr] *= al;
      }
    }
#pragma unroll
    for (int kc = 0; kc < 2; ++kc) {
#pragma unroll
      for (int ht = 0; ht < 5; ++ht) vB[ht] = *(const us8*)(vptr + ht * 512);
      vptr += 2560;  // final iteration's overrun frame lands in the (allocated) dm region
#pragma unroll
      for (int g = 0; g < 2; ++g) {
        float nm = -mrun[g] * L2E;
        float p0[4], p1[4];
#pragma unroll
        for (int rr = 0; rr < 4; ++rr) {
          p0[rr] = fast_exp2(__builtin_fmaf(sacc[g][2 * kc][rr], L2E, nm));
          p1[rr] = fast_exp2(__builtin_fmaf(sacc[g][2 * kc + 1][rr], L2E, nm));
        }
        u32x4 pw = {__builtin_bit_cast(u32, __builtin_amdgcn_cvt_pkrtz(p0[0], p0[1])),
                    __builtin_bit_cast(u32, __builtin_amdgcn_cvt_pkrtz(p0[2], p0[3])),
                    __builtin_bit_cast(u32, __builtin_amdgcn_cvt_pkrtz(p1[0], p1[1])),
                    __builtin_bit_cast(u32, __builtin_amdgcn_cvt_pkrtz(p1[2], p1[3]))};
        f16x8 pb = __builtin_bit_cast(f16x8, pw);
#pragma unroll
        for (int ht = 0; ht < 5; ++ht)
          oacc[g][ht] = __builtin_amdgcn_mfma_f32_16x16x32_f16(
              __builtin_bit_cast(f16x8, vA[ht]), pb, oacc[g][ht], 0, 0, 0);
      }
#pragma unroll
      for (int ht = 0; ht < 5; ++ht) vA[ht] = vB[ht];
    }
  }
#pragma unroll
  for (int g = 0; g < 2; ++g) {
    float den = __shfl(oacc[g][4][0], lo + 32, 64);  // h=72 ones-row -> denominator
    float inv = 1.f / den;
    int row = qb * 128 + w * 32 + g * 16 + lo;
    u16* orow = pbuf + ((size_t)half * LSEQ + row) * DMODEL + head * HD;
#pragma unroll
    for (int ht = 0; ht < 5; ++ht)
#pragma unroll
      for (int rr = 0; rr < 4; ++rr) {
        int h = 16 * ht + 4 * hi + rr;
        if (h < HD) orow[h] = f2h(oacc[g][ht][rr] * inv);
      }
    if (hi == 0) {
      float2 dm; dm.x = den; dm.y = mrun[g];
      dmb[((size_t)half * NH + head) * LSEQ + row] = dm;
    }
  }
}

// ---------------- combine the two key-half partials ----------------
// Kept as a separate 4096-block kernel: full TLP makes it nearly free (~5 us);
// fusing it into the 288-block O-proj GEMM measured -15 us (R15).
__global__ __launch_bounds__(384) void k_combine(
    const u16* __restrict__ pbuf, const float2* __restrict__ dmb, u16* __restrict__ attb) {
  const float L2E = 1.4426950408889634f;
  int tok = blockIdx.x, t = threadIdx.x;
  for (int c = t; c < DMODEL; c += 384) {
    int head = c / HD;
    float2 dm0 = dmb[(size_t)head * LSEQ + tok];
    float2 dm1 = dmb[((size_t)NH + head) * LSEQ + tok];
    float M = fmaxf(dm0.y, dm1.y);
    float w0 = dm0.x * fast_exp2((dm0.y - M) * L2E);
    float w1 = dm1.x * fast_exp2((dm1.y - M) * L2E);
    float o0 = h2f(pbuf[(size_t)tok * DMODEL + c]);
    float o1 = h2f(pbuf[((size_t)LSEQ + tok) * DMODEL + c]);
    attb[(size_t)tok * DMODEL + c] = f2h((w0 * o0 + w1 * o1) / (w0 + w1));
  }
}

extern "C" void kernel_launch(void* const* d_in, const int* in_sizes, int n_in,
                              void* d_out, int out_size, void* d_ws, size_t ws_size,
                              hipStream_t stream) {
  const float* x    = (const float*)d_in[0];
  const float* q_w  = (const float*)d_in[1];
  const float* q_b  = (const float*)d_in[2];
  const float* kv_w = (const float*)d_in[3];
  const float* kv_b = (const float*)d_in[4];
  const float* o_w  = (const float*)d_in[5];
  const float* o_b  = (const float*)d_in[6];
  const float* q_s  = (const float*)d_in[7];
  const float* k_s  = (const float*)d_in[8];
  char* ws = (char*)d_ws;
  // layout (bytes), high-water 84,017,152:
  u16* wT   = (u16*)(ws + 9437184);    // 7,962,624    [q_w^T; kv_w^T] f16 [3456][1152]
  u16* oT   = (u16*)(ws + 17399808);   // 2,654,208    o_w^T (live until GEMM2)
  u16* qkvb = (u16*)(ws + 20054016);   // 28,311,552   qkv pre-norm [4096][3456]
  u16* qp   = (u16*)(ws + 48365568);   // 12,582,912   q head-major [16][4096][96]
  u16* kp   = (u16*)(ws + 60948480);   // 12,582,912   k head-major
  u16* vn   = (u16*)(ws + 73531392);   // 10,485,760   v head-major [16][4096][80]
  u16* vfb  = (u16*)(ws + 0);          // 10,485,760   V fragment-major
  float2* dmb = (float2*)(ws + 10485760); // 1,048,576 (d,m) partials [2][16][4096]
  u16* attb = (u16*)(ws + 20054016);   // 9,437,184    attn out (reuses qkvb head)
  u16* pbuf = (u16*)(ws + 29491200);   // 18,874,368   o-hat partials [2][4096][1152]

  k_transp_w<<<dim3(36, 36), 256, 0, stream>>>(q_w, wT, DMODEL, DMODEL);
  k_transp_w<<<dim3(72, 36), 256, 0, stream>>>(kv_w, wT + (size_t)DMODEL * DMODEL, DMODEL, 2 * DMODEL);
  k_transp_w<<<dim3(36, 36), 256, 0, stream>>>(o_w, oT, DMODEL, DMODEL);
  // QKV GEMM: A = x (f32, cast fused into staging); grid 864 = 27x32, XCD-swizzled.
  k_gemm_bt<false, true><<<864, 256, 0, stream>>>(x, wT, nullptr, qkvb,
                                                  LSEQ, NQKV, DMODEL, 27, 864);
  k_norm_rope<<<LSEQ, 256, 0, stream>>>(qkvb, q_b, kv_b, q_s, k_s, qp, kp, vn);
  k_vfrag<<<dim3(128, 16), 256, 0, stream>>>(vn, vfb);
  k_flash<<<1024, 256, 0, stream>>>(qp, kp, vfb, pbuf, dmb);
  k_combine<<<LSEQ, 384, 0, stream>>>(pbuf, dmb, attb);
  // O-proj GEMM: A = attb (f16); grid 288 = 9x32, XCD-swizzled.
  k_gemm_bt<true, false><<<288, 256, 0, stream>>>(attb, oT, o_b, (float*)d_out,
                                                  LSEQ, DMODEL, DMODEL, 9, 288);
}